// Round 1
// baseline (440.677 us; speedup 1.0000x reference)
//
#include <hip/hip_runtime.h>
#include <stdint.h>

#define NH 12
#define HD64 64
#define SEQ 1025
#define M_ROWS (16 * SEQ)   // 16400
#define DIM 768
#define NPAD 1088           // 17 * 64, keeps V^T rows 16B-aligned

typedef __attribute__((ext_vector_type(8))) short bf16x8;
typedef __attribute__((ext_vector_type(4))) float f32x4;
typedef __attribute__((ext_vector_type(4))) short s16x4;

__device__ __forceinline__ short f2bf_rne(float f) {
    union { float f; uint32_t u; } c; c.f = f;
    uint32_t u = c.u + 0x7fffu + ((c.u >> 16) & 1u);
    return (short)(u >> 16);
}

__device__ __forceinline__ void gload_lds16(const void* g, void* l) {
    __builtin_amdgcn_global_load_lds(
        (const __attribute__((address_space(1))) void*)g,
        (__attribute__((address_space(3))) void*)l, 16, 0, 0);
}

// ---------------- fp32 -> bf16 conversion ----------------
__global__ void f2bf_kernel(const float* __restrict__ in, short* __restrict__ out, int n4) {
    int i = blockIdx.x * blockDim.x + threadIdx.x;
    if (i < n4) {
        f32x4 f = ((const f32x4*)in)[i];
        s16x4 o;
        o[0] = f2bf_rne(f[0]); o[1] = f2bf_rne(f[1]);
        o[2] = f2bf_rne(f[2]); o[3] = f2bf_rne(f[3]);
        ((s16x4*)out)[i] = o;
    }
}

// ---------------- QKV GEMM + RoPE epilogue ----------------
// C[m][e] = sum_d x[m][d] * Wqkv[e][d]; m = b*1025+n, e = qkv*768 + h*64 + d
__global__ __launch_bounds__(256) void qkv_gemm_kernel(
    const short* __restrict__ xb, const short* __restrict__ wb,
    const float* __restrict__ fcos, const float* __restrict__ fsin,
    short* __restrict__ Qb, short* __restrict__ Kb, short* __restrict__ VTb)
{
    __shared__ short Alds[128 * 32];
    __shared__ short Blds[128 * 32];
    const int tid = threadIdx.x;
    const int lane = tid & 63, w = tid >> 6;
    const int wm = w >> 1, wn = w & 1;
    const int lr = lane & 15, lg = lane >> 4;
    const int mt = blockIdx.x, nt = blockIdx.y;

    f32x4 acc[4][4];
#pragma unroll
    for (int i = 0; i < 4; i++)
#pragma unroll
        for (int j = 0; j < 4; j++) acc[i][j] = (f32x4)0.0f;

    for (int kt = 0; kt < 24; ++kt) {
        __syncthreads();
#pragma unroll
        for (int i = 0; i < 2; i++) {
            int c = i * 256 + tid;
            int row = c >> 2, cc = c & 3;
            int gr = mt * 128 + row; if (gr > M_ROWS - 1) gr = M_ROWS - 1;
            gload_lds16(xb + (size_t)gr * DIM + kt * 32 + cc * 8, Alds + c * 8);
            int gb = nt * 128 + row;   // < 2304 always
            gload_lds16(wb + (size_t)gb * DIM + kt * 32 + cc * 8, Blds + c * 8);
        }
        asm volatile("s_waitcnt vmcnt(0)" ::: "memory");
        __syncthreads();

        bf16x8 af[4], bfr[4];
#pragma unroll
        for (int mi = 0; mi < 4; mi++)
            af[mi] = *(const bf16x8*)&Alds[(wm * 64 + mi * 16 + lr) * 32 + lg * 8];
#pragma unroll
        for (int ni = 0; ni < 4; ni++)
            bfr[ni] = *(const bf16x8*)&Blds[(wn * 64 + ni * 16 + lr) * 32 + lg * 8];
#pragma unroll
        for (int mi = 0; mi < 4; mi++)
#pragma unroll
            for (int ni = 0; ni < 4; ni++)
                acc[mi][ni] = __builtin_amdgcn_mfma_f32_16x16x32_bf16(af[mi], bfr[ni], acc[mi][ni], 0, 0, 0);
    }

    // epilogue: RoPE (pairs are adjacent cols = lane^1), scale Q, scatter
#pragma unroll
    for (int ni = 0; ni < 4; ni++) {
        int e = nt * 128 + wn * 64 + ni * 16 + lr;
        int qkv = e / DIM;
        int rem = e - qkv * DIM;
        int h = rem >> 6, d = rem & 63;
#pragma unroll
        for (int mi = 0; mi < 4; mi++) {
            f32x4 v4 = acc[mi][ni];
#pragma unroll
            for (int j = 0; j < 4; j++) {
                int m = mt * 128 + wm * 64 + mi * 16 + lg * 4 + j;
                float v = v4[j];
                float vo = __shfl_xor(v, 1);       // partner col e^1 (uniform exec)
                bool valid = (m < M_ROWS);
                int mm = valid ? m : 0;
                int b = mm / SEQ;
                int n = mm - b * SEQ;
                float outv = v;
                if (qkv < 2 && n > 0) {
                    float cs = fcos[(n - 1) * 32 + (d >> 1)];
                    float sn = fsin[(n - 1) * 32 + (d >> 1)];
                    outv = (d & 1) ? (vo * sn + v * cs) : (v * cs - vo * sn);
                }
                if (qkv == 0) outv *= 0.125f;      // fold 1/sqrt(64) into Q
                if (valid) {
                    short bv = f2bf_rne(outv);
                    size_t bh = (size_t)b * NH + h;
                    if (qkv == 0)      Qb[(bh * SEQ + n) * HD64 + d] = bv;
                    else if (qkv == 1) Kb[(bh * SEQ + n) * HD64 + d] = bv;
                    else               VTb[(bh * HD64 + d) * NPAD + n] = bv;
                }
            }
        }
    }
}

// ---------------- flash attention ----------------
// grid (17, 192): x = q-tile of 64 rows, y = b*12+h. 4 waves, each 16 q-rows.
__global__ __launch_bounds__(256) void attn_kernel(
    const short* __restrict__ Qb, const short* __restrict__ Kb,
    const short* __restrict__ VTb, short* __restrict__ AO)
{
    __shared__ short Klds[64 * 64];
    __shared__ short Vlds[64 * 64];
    __shared__ short Plds[4][16 * 64];
    const int tid = threadIdx.x;
    const int lane = tid & 63, w = tid >> 6;
    const int lr = lane & 15, lg = lane >> 4;
    const int qt = blockIdx.x, bh = blockIdx.y;
    const int b = bh / NH, h = bh - b * NH;

    const short* Qp = Qb + (size_t)bh * SEQ * HD64;
    const short* Kp = Kb + (size_t)bh * SEQ * HD64;
    const short* Vp = VTb + (size_t)bh * HD64 * NPAD;

    int qr = qt * 64 + w * 16 + lr; if (qr > SEQ - 1) qr = SEQ - 1;
    bf16x8 qf0 = *(const bf16x8*)&Qp[(size_t)qr * HD64 + 0 + lg * 8];
    bf16x8 qf1 = *(const bf16x8*)&Qp[(size_t)qr * HD64 + 32 + lg * 8];

    float m_i[4], l_i[4];
    f32x4 acc[4];
#pragma unroll
    for (int j = 0; j < 4; j++) { m_i[j] = -1e30f; l_i[j] = 0.f; }
#pragma unroll
    for (int vt = 0; vt < 4; vt++) acc[vt] = (f32x4)0.0f;

    for (int t = 0; t < 17; ++t) {
        __syncthreads();
        int k0 = t * 64;
        // stage K [64 keys][64 d] and V^T [64 d][64 keys]; XOR-swizzled source so
        // linear global_load_lds dest + swizzled ds_read are conflict-free (G21)
#pragma unroll
        for (int i = 0; i < 2; i++) {
            int c = i * 256 + tid;
            int row = c >> 3, ccd = c & 7;
            int cl = ccd ^ (row & 7);
            int krow = k0 + row; if (krow > SEQ - 1) krow = SEQ - 1;
            gload_lds16(Kp + (size_t)krow * HD64 + cl * 8, Klds + c * 8);
            gload_lds16(Vp + (size_t)row * NPAD + k0 + cl * 8, Vlds + c * 8);
        }
        asm volatile("s_waitcnt vmcnt(0)" ::: "memory");
        __syncthreads();

        // QK^T: D[q][key], col = key_sub = lr
        f32x4 s[4];
#pragma unroll
        for (int k16 = 0; k16 < 4; k16++) {
            int krow = k16 * 16 + lr;
            bf16x8 kf0 = *(const bf16x8*)&Klds[krow * 64 + ((0 + lg) ^ (krow & 7)) * 8];
            bf16x8 kf1 = *(const bf16x8*)&Klds[krow * 64 + ((4 + lg) ^ (krow & 7)) * 8];
            f32x4 d = (f32x4)0.0f;
            d = __builtin_amdgcn_mfma_f32_16x16x32_bf16(qf0, kf0, d, 0, 0, 0);
            d = __builtin_amdgcn_mfma_f32_16x16x32_bf16(qf1, kf1, d, 0, 0, 0);
            if (k0 + krow > SEQ - 1) { d[0] = -1e30f; d[1] = -1e30f; d[2] = -1e30f; d[3] = -1e30f; }
            s[k16] = d;
        }

        // online softmax per q-row j (row = lg*4+j; reduce over 16 key-lanes)
#pragma unroll
        for (int j = 0; j < 4; j++) {
            float mx = fmaxf(fmaxf(s[0][j], s[1][j]), fmaxf(s[2][j], s[3][j]));
            mx = fmaxf(mx, __shfl_xor(mx, 1));
            mx = fmaxf(mx, __shfl_xor(mx, 2));
            mx = fmaxf(mx, __shfl_xor(mx, 4));
            mx = fmaxf(mx, __shfl_xor(mx, 8));
            float mnew = fmaxf(m_i[j], mx);
            float sc = __expf(m_i[j] - mnew);
            m_i[j] = mnew;
            float rs = 0.f;
#pragma unroll
            for (int k16 = 0; k16 < 4; k16++) {
                float p = __expf(s[k16][j] - mnew);
                s[k16][j] = p;
                rs += p;
            }
            rs += __shfl_xor(rs, 1); rs += __shfl_xor(rs, 2);
            rs += __shfl_xor(rs, 4); rs += __shfl_xor(rs, 8);
            l_i[j] = l_i[j] * sc + rs;
            acc[0][j] *= sc; acc[1][j] *= sc; acc[2][j] *= sc; acc[3][j] *= sc;
        }

        // P -> per-wave LDS (swizzled), re-layout for PV A-fragment
        short* pw = &Plds[w][0];
#pragma unroll
        for (int k16 = 0; k16 < 4; k16++) {
#pragma unroll
            for (int j = 0; j < 4; j++) {
                int q = lg * 4 + j;
                int col = k16 * 16 + lr;
                int phys = (col >> 3) ^ (q & 7);
                pw[q * 64 + phys * 8 + (col & 7)] = f2bf_rne(s[k16][j]);
            }
        }

        bf16x8 pa0 = *(const bf16x8*)&pw[lr * 64 + ((0 + lg) ^ (lr & 7)) * 8];
        bf16x8 pa1 = *(const bf16x8*)&pw[lr * 64 + ((4 + lg) ^ (lr & 7)) * 8];
#pragma unroll
        for (int vt = 0; vt < 4; vt++) {
            int dr = vt * 16 + lr;
            bf16x8 vf0 = *(const bf16x8*)&Vlds[dr * 64 + ((0 + lg) ^ (dr & 7)) * 8];
            bf16x8 vf1 = *(const bf16x8*)&Vlds[dr * 64 + ((4 + lg) ^ (dr & 7)) * 8];
            acc[vt] = __builtin_amdgcn_mfma_f32_16x16x32_bf16(pa0, vf0, acc[vt], 0, 0, 0);
            acc[vt] = __builtin_amdgcn_mfma_f32_16x16x32_bf16(pa1, vf1, acc[vt], 0, 0, 0);
        }
    }

    // store attn out: [b*1025+q][h*64 + d] bf16
#pragma unroll
    for (int vt = 0; vt < 4; vt++) {
#pragma unroll
        for (int j = 0; j < 4; j++) {
            int qrow = qt * 64 + w * 16 + lg * 4 + j;
            if (qrow < SEQ) {
                AO[((size_t)(b * SEQ + qrow)) * DIM + h * HD64 + vt * 16 + lr] =
                    f2bf_rne(acc[vt][j] / l_i[j]);
            }
        }
    }
}

// ---------------- output projection GEMM + bias ----------------
__global__ __launch_bounds__(256) void proj_gemm_kernel(
    const short* __restrict__ ab, const short* __restrict__ wb,
    const float* __restrict__ bias, float* __restrict__ out)
{
    __shared__ short Alds[128 * 32];
    __shared__ short Blds[128 * 32];
    const int tid = threadIdx.x;
    const int lane = tid & 63, w = tid >> 6;
    const int wm = w >> 1, wn = w & 1;
    const int lr = lane & 15, lg = lane >> 4;
    const int mt = blockIdx.x, nt = blockIdx.y;

    f32x4 acc[4][4];
#pragma unroll
    for (int i = 0; i < 4; i++)
#pragma unroll
        for (int j = 0; j < 4; j++) acc[i][j] = (f32x4)0.0f;

    for (int kt = 0; kt < 24; ++kt) {
        __syncthreads();
#pragma unroll
        for (int i = 0; i < 2; i++) {
            int c = i * 256 + tid;
            int row = c >> 2, cc = c & 3;
            int gr = mt * 128 + row; if (gr > M_ROWS - 1) gr = M_ROWS - 1;
            gload_lds16(ab + (size_t)gr * DIM + kt * 32 + cc * 8, Alds + c * 8);
            int gb = nt * 128 + row;   // < 768 always
            gload_lds16(wb + (size_t)gb * DIM + kt * 32 + cc * 8, Blds + c * 8);
        }
        asm volatile("s_waitcnt vmcnt(0)" ::: "memory");
        __syncthreads();

        bf16x8 af[4], bfr[4];
#pragma unroll
        for (int mi = 0; mi < 4; mi++)
            af[mi] = *(const bf16x8*)&Alds[(wm * 64 + mi * 16 + lr) * 32 + lg * 8];
#pragma unroll
        for (int ni = 0; ni < 4; ni++)
            bfr[ni] = *(const bf16x8*)&Blds[(wn * 64 + ni * 16 + lr) * 32 + lg * 8];
#pragma unroll
        for (int mi = 0; mi < 4; mi++)
#pragma unroll
            for (int ni = 0; ni < 4; ni++)
                acc[mi][ni] = __builtin_amdgcn_mfma_f32_16x16x32_bf16(af[mi], bfr[ni], acc[mi][ni], 0, 0, 0);
    }

#pragma unroll
    for (int ni = 0; ni < 4; ni++) {
        int e = nt * 128 + wn * 64 + ni * 16 + lr;
        float bv = bias[e];
#pragma unroll
        for (int mi = 0; mi < 4; mi++) {
#pragma unroll
            for (int j = 0; j < 4; j++) {
                int m = mt * 128 + wm * 64 + mi * 16 + lg * 4 + j;
                if (m < M_ROWS) out[(size_t)m * DIM + e] = acc[mi][ni][j] + bv;
            }
        }
    }
}

extern "C" void kernel_launch(void* const* d_in, const int* in_sizes, int n_in,
                              void* d_out, int out_size, void* d_ws, size_t ws_size,
                              hipStream_t stream) {
    const float* x     = (const float*)d_in[0];
    const float* fcos  = (const float*)d_in[1];
    const float* fsin  = (const float*)d_in[2];
    const float* wqkv  = (const float*)d_in[3];
    const float* wproj = (const float*)d_in[4];
    const float* bproj = (const float*)d_in[5];
    float* out = (float*)d_out;

    char* ws = (char*)d_ws;
    size_t off = 0;
    auto salloc = [&](size_t bytes) { void* p = ws + off; off += (bytes + 255) & ~(size_t)255; return p; };
    short* xb     = (short*)salloc((size_t)M_ROWS * DIM * 2);
    short* wqkvb  = (short*)salloc((size_t)2304 * DIM * 2);
    short* wprojb = (short*)salloc((size_t)DIM * DIM * 2);
    short* Qb     = (short*)salloc((size_t)192 * SEQ * HD64 * 2);
    short* Kb     = (short*)salloc((size_t)192 * SEQ * HD64 * 2);
    short* VTb    = (short*)salloc((size_t)192 * HD64 * NPAD * 2);
    short* AO     = (short*)salloc((size_t)M_ROWS * DIM * 2);

    {
        int n4 = M_ROWS * DIM / 4;
        f2bf_kernel<<<(n4 + 255) / 256, 256, 0, stream>>>(x, xb, n4);
    }
    {
        int n4 = 2304 * DIM / 4;
        f2bf_kernel<<<(n4 + 255) / 256, 256, 0, stream>>>(wqkv, wqkvb, n4);
    }
    {
        int n4 = DIM * DIM / 4;
        f2bf_kernel<<<(n4 + 255) / 256, 256, 0, stream>>>(wproj, wprojb, n4);
    }

    qkv_gemm_kernel<<<dim3(129, 18), 256, 0, stream>>>(xb, wqkvb, fcos, fsin, Qb, Kb, VTb);
    attn_kernel<<<dim3(17, 192), 256, 0, stream>>>(Qb, Kb, VTb, AO);
    proj_gemm_kernel<<<dim3(129, 6), 256, 0, stream>>>(AO, wprojb, bproj, out);
}

// Round 2
// 382.196 us; speedup vs baseline: 1.1530x; 1.1530x over previous
//
#include <hip/hip_runtime.h>
#include <stdint.h>

#define NH 12
#define HD64 64
#define SEQ 1025
#define M_ROWS (16 * SEQ)   // 16400
#define DIM 768
#define NPAD 1088           // 17 * 64, keeps V^T rows 16B-aligned

typedef __attribute__((ext_vector_type(8))) short bf16x8;
typedef __attribute__((ext_vector_type(4))) float f32x4;
typedef __attribute__((ext_vector_type(4))) short s16x4;

__device__ __forceinline__ short f2bf_rne(float f) {
    union { float f; uint32_t u; } c; c.f = f;
    uint32_t u = c.u + 0x7fffu + ((c.u >> 16) & 1u);
    return (short)(u >> 16);
}

__device__ __forceinline__ int cvt_pk_bf16(float lo, float hi) {
    int r;
    asm("v_cvt_pk_bf16_f32 %0, %1, %2" : "=v"(r) : "v"(lo), "v"(hi));
    return r;
}

__device__ __forceinline__ void gload_lds16(const void* g, void* l) {
    __builtin_amdgcn_global_load_lds(
        (const __attribute__((address_space(1))) void*)g,
        (__attribute__((address_space(3))) void*)l, 16, 0, 0);
}

// ---------------- fp32 -> bf16 conversion ----------------
__global__ void f2bf_kernel(const float* __restrict__ in, short* __restrict__ out, int n4) {
    int i = blockIdx.x * blockDim.x + threadIdx.x;
    if (i < n4) {
        f32x4 f = ((const f32x4*)in)[i];
        s16x4 o;
        o[0] = f2bf_rne(f[0]); o[1] = f2bf_rne(f[1]);
        o[2] = f2bf_rne(f[2]); o[3] = f2bf_rne(f[3]);
        ((s16x4*)out)[i] = o;
    }
}

// ---------------- QKV GEMM + RoPE epilogue ----------------
// C[m][e] = sum_d x[m][d] * Wqkv[e][d]; m = b*1025+n, e = qkv*768 + h*64 + d
// Q is scaled by 0.125 * log2(e) so attention can use exp2 directly.
__global__ __launch_bounds__(256) void qkv_gemm_kernel(
    const short* __restrict__ xb, const short* __restrict__ wb,
    const float* __restrict__ fcos, const float* __restrict__ fsin,
    short* __restrict__ Qb, short* __restrict__ Kb, short* __restrict__ VTb)
{
    __shared__ short Alds[128 * 32];
    __shared__ short Blds[128 * 32];
    const int tid = threadIdx.x;
    const int lane = tid & 63, w = tid >> 6;
    const int wm = w >> 1, wn = w & 1;
    const int lr = lane & 15, lg = lane >> 4;
    const int mt = blockIdx.x, nt = blockIdx.y;

    f32x4 acc[4][4];
#pragma unroll
    for (int i = 0; i < 4; i++)
#pragma unroll
        for (int j = 0; j < 4; j++) acc[i][j] = (f32x4)0.0f;

    for (int kt = 0; kt < 24; ++kt) {
        __syncthreads();
#pragma unroll
        for (int i = 0; i < 2; i++) {
            int c = i * 256 + tid;
            int row = c >> 2, cc = c & 3;
            int gr = mt * 128 + row; if (gr > M_ROWS - 1) gr = M_ROWS - 1;
            gload_lds16(xb + (size_t)gr * DIM + kt * 32 + cc * 8, Alds + c * 8);
            int gb = nt * 128 + row;   // < 2304 always
            gload_lds16(wb + (size_t)gb * DIM + kt * 32 + cc * 8, Blds + c * 8);
        }
        asm volatile("s_waitcnt vmcnt(0)" ::: "memory");
        __syncthreads();

        bf16x8 af[4], bfr[4];
#pragma unroll
        for (int mi = 0; mi < 4; mi++)
            af[mi] = *(const bf16x8*)&Alds[(wm * 64 + mi * 16 + lr) * 32 + lg * 8];
#pragma unroll
        for (int ni = 0; ni < 4; ni++)
            bfr[ni] = *(const bf16x8*)&Blds[(wn * 64 + ni * 16 + lr) * 32 + lg * 8];
#pragma unroll
        for (int mi = 0; mi < 4; mi++)
#pragma unroll
            for (int ni = 0; ni < 4; ni++)
                acc[mi][ni] = __builtin_amdgcn_mfma_f32_16x16x32_bf16(af[mi], bfr[ni], acc[mi][ni], 0, 0, 0);
    }

    // epilogue: RoPE (pairs are adjacent cols = lane^1), scale Q, scatter
#pragma unroll
    for (int ni = 0; ni < 4; ni++) {
        int e = nt * 128 + wn * 64 + ni * 16 + lr;
        int qkv = e / DIM;
        int rem = e - qkv * DIM;
        int h = rem >> 6, d = rem & 63;
#pragma unroll
        for (int mi = 0; mi < 4; mi++) {
            f32x4 v4 = acc[mi][ni];
#pragma unroll
            for (int j = 0; j < 4; j++) {
                int m = mt * 128 + wm * 64 + mi * 16 + lg * 4 + j;
                float v = v4[j];
                float vo = __shfl_xor(v, 1);       // partner col e^1 (uniform exec)
                bool valid = (m < M_ROWS);
                int mm = valid ? m : 0;
                int b = mm / SEQ;
                int n = mm - b * SEQ;
                float outv = v;
                if (qkv < 2 && n > 0) {
                    float cs = fcos[(n - 1) * 32 + (d >> 1)];
                    float sn = fsin[(n - 1) * 32 + (d >> 1)];
                    outv = (d & 1) ? (vo * sn + v * cs) : (v * cs - vo * sn);
                }
                if (qkv == 0) outv *= 0.180336881f;   // 1/sqrt(64) * log2(e)
                if (valid) {
                    short bv = f2bf_rne(outv);
                    size_t bh = (size_t)b * NH + h;
                    if (qkv == 0)      Qb[(bh * SEQ + n) * HD64 + d] = bv;
                    else if (qkv == 1) Kb[(bh * SEQ + n) * HD64 + d] = bv;
                    else               VTb[(bh * HD64 + d) * NPAD + n] = bv;
                }
            }
        }
    }
}

// ---------------- flash attention ----------------
// grid (17, 192): x = q-tile of 64 rows, y = b*12+h. 4 waves, each 16 q-rows.
// Swapped QK^T: D = P[key][q], q = lane&15 lane-local -> in-register softmax.
__global__ __launch_bounds__(256) void attn_kernel(
    const short* __restrict__ Qb, const short* __restrict__ Kb,
    const short* __restrict__ VTb, short* __restrict__ AO)
{
    __shared__ short Klds[64 * 64];
    __shared__ short Vlds[64 * 64];
    __shared__ int Plds[4][16 * 32];   // per-wave P exchange: [q=lr][32 key-pair dwords]
    const int tid = threadIdx.x;
    const int lane = tid & 63, w = tid >> 6;
    const int lr = lane & 15, lg = lane >> 4;
    const int qt = blockIdx.x, bh = blockIdx.y;
    const int b = bh / NH, h = bh - b * NH;

    const short* Qp = Qb + (size_t)bh * SEQ * HD64;
    const short* Kp = Kb + (size_t)bh * SEQ * HD64;
    const short* Vp = VTb + (size_t)bh * HD64 * NPAD;

    int qr = qt * 64 + w * 16 + lr; if (qr > SEQ - 1) qr = SEQ - 1;
    bf16x8 qf0 = *(const bf16x8*)&Qp[(size_t)qr * HD64 + 0 + lg * 8];
    bf16x8 qf1 = *(const bf16x8*)&Qp[(size_t)qr * HD64 + 32 + lg * 8];

    float m_i = -1e30f, l_i = 0.f;      // per-lane scalars, q = lr
    f32x4 acc[4];
#pragma unroll
    for (int vt = 0; vt < 4; vt++) acc[vt] = (f32x4)0.0f;

    int* pw = &Plds[w][0];
    const int pswz = (lr & 3) << 3;     // xor-swizzle on key-pair index (bits 3,4)

    for (int t = 0; t < 17; ++t) {
        __syncthreads();
        int k0 = t * 64;
#pragma unroll
        for (int i = 0; i < 2; i++) {
            int c = i * 256 + tid;
            int row = c >> 3, ccd = c & 7;
            int cl = ccd ^ (row & 7);
            int krow = k0 + row; if (krow > SEQ - 1) krow = SEQ - 1;
            gload_lds16(Kp + (size_t)krow * HD64 + cl * 8, Klds + c * 8);
            gload_lds16(Vp + (size_t)row * NPAD + k0 + cl * 8, Vlds + c * 8);
        }
        asm volatile("s_waitcnt vmcnt(0)" ::: "memory");
        __syncthreads();

        // swapped QK^T: s[k16] rows = key = k16*16 + lg*4 + j, col q = lr
        f32x4 s[4];
#pragma unroll
        for (int k16 = 0; k16 < 4; k16++) {
            int krow = k16 * 16 + lr;   // A-frag row this lane LOADS
            bf16x8 kf0 = *(const bf16x8*)&Klds[krow * 64 + ((0 + lg) ^ (krow & 7)) * 8];
            bf16x8 kf1 = *(const bf16x8*)&Klds[krow * 64 + ((4 + lg) ^ (krow & 7)) * 8];
            f32x4 d = (f32x4)0.0f;
            d = __builtin_amdgcn_mfma_f32_16x16x32_bf16(kf0, qf0, d, 0, 0, 0);
            d = __builtin_amdgcn_mfma_f32_16x16x32_bf16(kf1, qf1, d, 0, 0, 0);
            s[k16] = d;
        }
        if (t == 16) {
            // only key 1024 (k16==0, lg==0, j==0) is valid
            s[0][0] = (lg == 0) ? s[0][0] : -1e30f;
            s[0][1] = -1e30f; s[0][2] = -1e30f; s[0][3] = -1e30f;
#pragma unroll
            for (int k16 = 1; k16 < 4; k16++) { s[k16][0] = -1e30f; s[k16][1] = -1e30f; s[k16][2] = -1e30f; s[k16][3] = -1e30f; }
        }

        // local max tree over 16 values
        float a0 = fmaxf(s[0][0], s[0][1]), a1 = fmaxf(s[0][2], s[0][3]);
        float a2 = fmaxf(s[1][0], s[1][1]), a3 = fmaxf(s[1][2], s[1][3]);
        float a4 = fmaxf(s[2][0], s[2][1]), a5 = fmaxf(s[2][2], s[2][3]);
        float a6 = fmaxf(s[3][0], s[3][1]), a7 = fmaxf(s[3][2], s[3][3]);
        float b0 = fmaxf(fmaxf(a0, a1), fmaxf(a2, a3));
        float b1 = fmaxf(fmaxf(a4, a5), fmaxf(a6, a7));
        float pmax = fmaxf(b0, b1);
        pmax = fmaxf(pmax, __shfl_xor(pmax, 16));
        pmax = fmaxf(pmax, __shfl_xor(pmax, 32));

        // defer-max (T13): rescale only if some row grew past threshold (exp2 units)
        if (__any(pmax > m_i + 11.54f)) {
            float mnew = fmaxf(m_i, pmax);
            float sc = exp2f(m_i - mnew);
            m_i = mnew;
            l_i *= sc;
#pragma unroll
            for (int j = 0; j < 4; j++) {
                float scj = __shfl(sc, 4 * lg + j);   // sc for q = 4*lg+j lives at lane q
#pragma unroll
                for (int vt = 0; vt < 4; vt++) acc[vt][j] *= scj;
            }
        }

        // P = exp2(s - m), packed to bf16 pairs, rowsum
#pragma unroll
        for (int k16 = 0; k16 < 4; k16++) {
#pragma unroll
            for (int j = 0; j < 4; j++) s[k16][j] = exp2f(s[k16][j] - m_i);
        }
        float r0 = (s[0][0] + s[0][1]) + (s[0][2] + s[0][3]);
        float r1 = (s[1][0] + s[1][1]) + (s[1][2] + s[1][3]);
        float r2 = (s[2][0] + s[2][1]) + (s[2][2] + s[2][3]);
        float r3 = (s[3][0] + s[3][1]) + (s[3][2] + s[3][3]);
        float rowsum = (r0 + r1) + (r2 + r3);
        rowsum += __shfl_xor(rowsum, 16);
        rowsum += __shfl_xor(rowsum, 32);
        l_i += rowsum;

        // exchange P[key][q] -> A-frag P[q][key] via per-wave swizzled LDS
#pragma unroll
        for (int k16 = 0; k16 < 4; k16++) {
            int pk0 = cvt_pk_bf16(s[k16][0], s[k16][1]);
            int pk1 = cvt_pk_bf16(s[k16][2], s[k16][3]);
            int pbase = 8 * k16 + 2 * lg;
            pw[lr * 32 + ((pbase + 0) ^ pswz)] = pk0;
            pw[lr * 32 + ((pbase + 1) ^ pswz)] = pk1;
        }
        bf16x8 pa0 = *(const bf16x8*)&pw[lr * 32 + ((4 * lg) ^ pswz)];        // keys 0..31
        bf16x8 pa1 = *(const bf16x8*)&pw[lr * 32 + ((16 + 4 * lg) ^ pswz)];   // keys 32..63

#pragma unroll
        for (int vt = 0; vt < 4; vt++) {
            int dr = vt * 16 + lr;
            bf16x8 vf0 = *(const bf16x8*)&Vlds[dr * 64 + ((0 + lg) ^ (dr & 7)) * 8];
            bf16x8 vf1 = *(const bf16x8*)&Vlds[dr * 64 + ((4 + lg) ^ (dr & 7)) * 8];
            acc[vt] = __builtin_amdgcn_mfma_f32_16x16x32_bf16(pa0, vf0, acc[vt], 0, 0, 0);
            acc[vt] = __builtin_amdgcn_mfma_f32_16x16x32_bf16(pa1, vf1, acc[vt], 0, 0, 0);
        }
    }

    // store attn out: [b*1025+q][h*64 + d] bf16; gather l for q = lg*4+j
    float inv[4];
#pragma unroll
    for (int j = 0; j < 4; j++) inv[j] = 1.0f / __shfl(l_i, 4 * lg + j);
#pragma unroll
    for (int vt = 0; vt < 4; vt++) {
#pragma unroll
        for (int j = 0; j < 4; j++) {
            int qrow = qt * 64 + w * 16 + lg * 4 + j;
            if (qrow < SEQ) {
                AO[((size_t)(b * SEQ + qrow)) * DIM + h * HD64 + vt * 16 + lr] =
                    f2bf_rne(acc[vt][j] * inv[j]);
            }
        }
    }
}

// ---------------- output projection GEMM + bias ----------------
__global__ __launch_bounds__(256) void proj_gemm_kernel(
    const short* __restrict__ ab, const short* __restrict__ wb,
    const float* __restrict__ bias, float* __restrict__ out)
{
    __shared__ short Alds[128 * 32];
    __shared__ short Blds[128 * 32];
    const int tid = threadIdx.x;
    const int lane = tid & 63, w = tid >> 6;
    const int wm = w >> 1, wn = w & 1;
    const int lr = lane & 15, lg = lane >> 4;
    const int mt = blockIdx.x, nt = blockIdx.y;

    f32x4 acc[4][4];
#pragma unroll
    for (int i = 0; i < 4; i++)
#pragma unroll
        for (int j = 0; j < 4; j++) acc[i][j] = (f32x4)0.0f;

    for (int kt = 0; kt < 24; ++kt) {
        __syncthreads();
#pragma unroll
        for (int i = 0; i < 2; i++) {
            int c = i * 256 + tid;
            int row = c >> 2, cc = c & 3;
            int gr = mt * 128 + row; if (gr > M_ROWS - 1) gr = M_ROWS - 1;
            gload_lds16(ab + (size_t)gr * DIM + kt * 32 + cc * 8, Alds + c * 8);
            int gb = nt * 128 + row;   // < 768 always
            gload_lds16(wb + (size_t)gb * DIM + kt * 32 + cc * 8, Blds + c * 8);
        }
        asm volatile("s_waitcnt vmcnt(0)" ::: "memory");
        __syncthreads();

        bf16x8 af[4], bfr[4];
#pragma unroll
        for (int mi = 0; mi < 4; mi++)
            af[mi] = *(const bf16x8*)&Alds[(wm * 64 + mi * 16 + lr) * 32 + lg * 8];
#pragma unroll
        for (int ni = 0; ni < 4; ni++)
            bfr[ni] = *(const bf16x8*)&Blds[(wn * 64 + ni * 16 + lr) * 32 + lg * 8];
#pragma unroll
        for (int mi = 0; mi < 4; mi++)
#pragma unroll
            for (int ni = 0; ni < 4; ni++)
                acc[mi][ni] = __builtin_amdgcn_mfma_f32_16x16x32_bf16(af[mi], bfr[ni], acc[mi][ni], 0, 0, 0);
    }

#pragma unroll
    for (int ni = 0; ni < 4; ni++) {
        int e = nt * 128 + wn * 64 + ni * 16 + lr;
        float bv = bias[e];
#pragma unroll
        for (int mi = 0; mi < 4; mi++) {
#pragma unroll
            for (int j = 0; j < 4; j++) {
                int m = mt * 128 + wm * 64 + mi * 16 + lg * 4 + j;
                if (m < M_ROWS) out[(size_t)m * DIM + e] = acc[mi][ni][j] + bv;
            }
        }
    }
}

extern "C" void kernel_launch(void* const* d_in, const int* in_sizes, int n_in,
                              void* d_out, int out_size, void* d_ws, size_t ws_size,
                              hipStream_t stream) {
    const float* x     = (const float*)d_in[0];
    const float* fcos  = (const float*)d_in[1];
    const float* fsin  = (const float*)d_in[2];
    const float* wqkv  = (const float*)d_in[3];
    const float* wproj = (const float*)d_in[4];
    const float* bproj = (const float*)d_in[5];
    float* out = (float*)d_out;

    char* ws = (char*)d_ws;
    size_t off = 0;
    auto salloc = [&](size_t bytes) { void* p = ws + off; off += (bytes + 255) & ~(size_t)255; return p; };
    short* xb     = (short*)salloc((size_t)M_ROWS * DIM * 2);
    short* wqkvb  = (short*)salloc((size_t)2304 * DIM * 2);
    short* wprojb = (short*)salloc((size_t)DIM * DIM * 2);
    short* Qb     = (short*)salloc((size_t)192 * SEQ * HD64 * 2);
    short* Kb     = (short*)salloc((size_t)192 * SEQ * HD64 * 2);
    short* VTb    = (short*)salloc((size_t)192 * HD64 * NPAD * 2);
    short* AO     = (short*)salloc((size_t)M_ROWS * DIM * 2);

    {
        int n4 = M_ROWS * DIM / 4;
        f2bf_kernel<<<(n4 + 255) / 256, 256, 0, stream>>>(x, xb, n4);
    }
    {
        int n4 = 2304 * DIM / 4;
        f2bf_kernel<<<(n4 + 255) / 256, 256, 0, stream>>>(wqkv, wqkvb, n4);
    }
    {
        int n4 = DIM * DIM / 4;
        f2bf_kernel<<<(n4 + 255) / 256, 256, 0, stream>>>(wproj, wprojb, n4);
    }

    qkv_gemm_kernel<<<dim3(129, 18), 256, 0, stream>>>(xb, wqkvb, fcos, fsin, Qb, Kb, VTb);
    attn_kernel<<<dim3(17, 192), 256, 0, stream>>>(Qb, Kb, VTb, AO);
    proj_gemm_kernel<<<dim3(129, 6), 256, 0, stream>>>(AO, wprojb, bproj, out);
}

// Round 3
// 355.833 us; speedup vs baseline: 1.2384x; 1.0741x over previous
//
#include <hip/hip_runtime.h>
#include <stdint.h>

#define NH 12
#define HD64 64
#define SEQ 1025
#define M_ROWS (16 * SEQ)   // 16400
#define DIM 768
#define NPAD 1088           // 17 * 64, keeps V^T rows 16B-aligned

typedef __attribute__((ext_vector_type(8))) short bf16x8;
typedef __attribute__((ext_vector_type(4))) float f32x4;
typedef __attribute__((ext_vector_type(4))) short s16x4;

__device__ __forceinline__ short f2bf_rne(float f) {
    union { float f; uint32_t u; } c; c.f = f;
    uint32_t u = c.u + 0x7fffu + ((c.u >> 16) & 1u);
    return (short)(u >> 16);
}

__device__ __forceinline__ int cvt_pk_bf16(float lo, float hi) {
    int r;
    asm("v_cvt_pk_bf16_f32 %0, %1, %2" : "=v"(r) : "v"(lo), "v"(hi));
    return r;
}

__device__ __forceinline__ void gload_lds16(const void* g, void* l) {
    __builtin_amdgcn_global_load_lds(
        (const __attribute__((address_space(1))) void*)g,
        (__attribute__((address_space(3))) void*)l, 16, 0, 0);
}

// T1: XCD-chunked bijective swizzle (m204). HW round-robins blockIdx across 8
// XCDs; map so each XCD owns a CONTIGUOUS chunk of the logical tile order.
__device__ __forceinline__ int xcd_chunk_swizzle(int orig, int nwg) {
    int q = nwg >> 3, r = nwg & 7;
    int xcd = orig & 7, i = orig >> 3;
    int start = (xcd < r) ? xcd * (q + 1) : r * (q + 1) + (xcd - r) * q;
    return start + i;
}

// ---------------- fp32 -> bf16 conversion ----------------
__global__ void f2bf_kernel(const float* __restrict__ in, short* __restrict__ out, int n4) {
    int i = blockIdx.x * blockDim.x + threadIdx.x;
    if (i < n4) {
        f32x4 f = ((const f32x4*)in)[i];
        s16x4 o;
        o[0] = f2bf_rne(f[0]); o[1] = f2bf_rne(f[1]);
        o[2] = f2bf_rne(f[2]); o[3] = f2bf_rne(f[3]);
        ((s16x4*)out)[i] = o;
    }
}

// ---------------- QKV GEMM + RoPE epilogue ----------------
// C[m][e] = sum_d x[m][d] * Wqkv[e][d]; m = b*1025+n, e = qkv*768 + h*64 + d
// Q is scaled by 0.125 * log2(e) so attention can use exp2 directly.
// Double-buffered stage-ahead K-loop (T3-minimum); grid is 1D, n-tile fastest.
__global__ __launch_bounds__(256) void qkv_gemm_kernel(
    const short* __restrict__ xb, const short* __restrict__ wb,
    const float* __restrict__ fcos, const float* __restrict__ fsin,
    short* __restrict__ Qb, short* __restrict__ Kb, short* __restrict__ VTb)
{
    __shared__ short Alds[2][128 * 32];
    __shared__ short Blds[2][128 * 32];
    const int tid = threadIdx.x;
    const int lane = tid & 63, w = tid >> 6;
    const int wm = w >> 1, wn = w & 1;
    const int lr = lane & 15, lg = lane >> 4;
    const int tile = xcd_chunk_swizzle(blockIdx.x, 129 * 18);
    const int mt = tile / 18, nt = tile - (tile / 18) * 18;

    f32x4 acc[4][4];
#pragma unroll
    for (int i = 0; i < 4; i++)
#pragma unroll
        for (int j = 0; j < 4; j++) acc[i][j] = (f32x4)0.0f;

    auto stage = [&](int buf, int kt) {
#pragma unroll
        for (int i = 0; i < 2; i++) {
            int c = i * 256 + tid;
            int row = c >> 2, cc = c & 3;
            int gr = mt * 128 + row; if (gr > M_ROWS - 1) gr = M_ROWS - 1;
            gload_lds16(xb + (size_t)gr * DIM + kt * 32 + cc * 8, &Alds[buf][c * 8]);
            int gb = nt * 128 + row;   // < 2304 always
            gload_lds16(wb + (size_t)gb * DIM + kt * 32 + cc * 8, &Blds[buf][c * 8]);
        }
    };

    stage(0, 0);
    asm volatile("s_waitcnt vmcnt(0)" ::: "memory");
    __syncthreads();

    for (int kt = 0; kt < 24; ++kt) {
        int cur = kt & 1;
        if (kt < 23) stage(cur ^ 1, kt + 1);   // prefetch next tile under compute

        bf16x8 af[4], bfr[4];
#pragma unroll
        for (int mi = 0; mi < 4; mi++)
            af[mi] = *(const bf16x8*)&Alds[cur][(wm * 64 + mi * 16 + lr) * 32 + lg * 8];
#pragma unroll
        for (int ni = 0; ni < 4; ni++)
            bfr[ni] = *(const bf16x8*)&Blds[cur][(wn * 64 + ni * 16 + lr) * 32 + lg * 8];
#pragma unroll
        for (int mi = 0; mi < 4; mi++)
#pragma unroll
            for (int ni = 0; ni < 4; ni++)
                acc[mi][ni] = __builtin_amdgcn_mfma_f32_16x16x32_bf16(af[mi], bfr[ni], acc[mi][ni], 0, 0, 0);

        asm volatile("s_waitcnt vmcnt(0)" ::: "memory");
        __syncthreads();
    }

    // epilogue: RoPE (pairs are adjacent cols = lane^1), scale Q, scatter
#pragma unroll
    for (int mi = 0; mi < 4; mi++) {
        int mbase = mt * 128 + wm * 64 + mi * 16 + lg * 4;
#pragma unroll
        for (int j = 0; j < 4; j++) {
            int m = mbase + j;
            bool valid = (m < M_ROWS);
            int mm = valid ? m : 0;
            int b = mm / SEQ;
            int n = mm - b * SEQ;
#pragma unroll
            for (int ni = 0; ni < 4; ni++) {
                int e = nt * 128 + wn * 64 + ni * 16 + lr;
                int qkv = e / DIM;
                int rem = e - qkv * DIM;
                int h = rem >> 6, d = rem & 63;
                float v = acc[mi][ni][j];
                float vo = __shfl_xor(v, 1);       // partner col e^1 (uniform exec)
                float outv = v;
                if (qkv < 2 && n > 0) {
                    float cs = fcos[(n - 1) * 32 + (d >> 1)];
                    float sn = fsin[(n - 1) * 32 + (d >> 1)];
                    outv = (d & 1) ? (vo * sn + v * cs) : (v * cs - vo * sn);
                }
                if (qkv == 0) outv *= 0.180336881f;   // 1/sqrt(64) * log2(e)
                if (valid) {
                    short bv = f2bf_rne(outv);
                    size_t bh = (size_t)b * NH + h;
                    if (qkv == 0)      Qb[(bh * SEQ + n) * HD64 + d] = bv;
                    else if (qkv == 1) Kb[(bh * SEQ + n) * HD64 + d] = bv;
                    else               VTb[(bh * HD64 + d) * NPAD + n] = bv;
                }
            }
        }
    }
}

// ---------------- flash attention ----------------
// 1D grid 17*192, q-tile fastest in logical order (17 q-tiles of one head are
// XCD-adjacent -> K/V fetched once per XCD). 4 waves, each 16 q-rows.
// Swapped QK^T: D = P[key][q], q = lane&15 lane-local -> in-register softmax.
// Double-buffered K/V staging.
__global__ __launch_bounds__(256) void attn_kernel(
    const short* __restrict__ Qb, const short* __restrict__ Kb,
    const short* __restrict__ VTb, short* __restrict__ AO)
{
    __shared__ short Klds[2][64 * 64];
    __shared__ short Vlds[2][64 * 64];
    __shared__ int Plds[4][16 * 32];   // per-wave P exchange: [q=lr][32 key-pair dwords]
    const int tid = threadIdx.x;
    const int lane = tid & 63, w = tid >> 6;
    const int lr = lane & 15, lg = lane >> 4;
    const int tile = xcd_chunk_swizzle(blockIdx.x, 17 * 192);
    const int bh = tile / 17, qt = tile - (tile / 17) * 17;
    const int b = bh / NH, h = bh - b * NH;

    const short* Qp = Qb + (size_t)bh * SEQ * HD64;
    const short* Kp = Kb + (size_t)bh * SEQ * HD64;
    const short* Vp = VTb + (size_t)bh * HD64 * NPAD;

    int qr = qt * 64 + w * 16 + lr; if (qr > SEQ - 1) qr = SEQ - 1;
    bf16x8 qf0 = *(const bf16x8*)&Qp[(size_t)qr * HD64 + 0 + lg * 8];
    bf16x8 qf1 = *(const bf16x8*)&Qp[(size_t)qr * HD64 + 32 + lg * 8];

    float m_i = -1e30f, l_i = 0.f;      // per-lane scalars, q = lr
    f32x4 acc[4];
#pragma unroll
    for (int vt = 0; vt < 4; vt++) acc[vt] = (f32x4)0.0f;

    int* pw = &Plds[w][0];
    const int pswz = (lr & 3) << 3;     // xor-swizzle on key-pair index (bits 3,4)

    auto stageKV = [&](int buf, int t) {
        int k0 = t * 64;
#pragma unroll
        for (int i = 0; i < 2; i++) {
            int c = i * 256 + tid;
            int row = c >> 3, ccd = c & 7;
            int cl = ccd ^ (row & 7);
            int krow = k0 + row; if (krow > SEQ - 1) krow = SEQ - 1;
            gload_lds16(Kp + (size_t)krow * HD64 + cl * 8, &Klds[buf][c * 8]);
            gload_lds16(Vp + (size_t)row * NPAD + k0 + cl * 8, &Vlds[buf][c * 8]);
        }
    };

    stageKV(0, 0);
    asm volatile("s_waitcnt vmcnt(0)" ::: "memory");
    __syncthreads();

    for (int t = 0; t < 17; ++t) {
        int cur = t & 1;
        if (t < 16) stageKV(cur ^ 1, t + 1);   // prefetch next K/V under compute

        // swapped QK^T: s[k16] rows = key = k16*16 + lg*4 + j, col q = lr
        f32x4 s[4];
#pragma unroll
        for (int k16 = 0; k16 < 4; k16++) {
            int krow = k16 * 16 + lr;   // A-frag row this lane LOADS
            bf16x8 kf0 = *(const bf16x8*)&Klds[cur][krow * 64 + ((0 + lg) ^ (krow & 7)) * 8];
            bf16x8 kf1 = *(const bf16x8*)&Klds[cur][krow * 64 + ((4 + lg) ^ (krow & 7)) * 8];
            f32x4 d = (f32x4)0.0f;
            d = __builtin_amdgcn_mfma_f32_16x16x32_bf16(kf0, qf0, d, 0, 0, 0);
            d = __builtin_amdgcn_mfma_f32_16x16x32_bf16(kf1, qf1, d, 0, 0, 0);
            s[k16] = d;
        }
        if (t == 16) {
            // only key 1024 (k16==0, lg==0, j==0) is valid
            s[0][0] = (lg == 0) ? s[0][0] : -1e30f;
            s[0][1] = -1e30f; s[0][2] = -1e30f; s[0][3] = -1e30f;
#pragma unroll
            for (int k16 = 1; k16 < 4; k16++) { s[k16][0] = -1e30f; s[k16][1] = -1e30f; s[k16][2] = -1e30f; s[k16][3] = -1e30f; }
        }

        // local max tree over 16 values
        float a0 = fmaxf(s[0][0], s[0][1]), a1 = fmaxf(s[0][2], s[0][3]);
        float a2 = fmaxf(s[1][0], s[1][1]), a3 = fmaxf(s[1][2], s[1][3]);
        float a4 = fmaxf(s[2][0], s[2][1]), a5 = fmaxf(s[2][2], s[2][3]);
        float a6 = fmaxf(s[3][0], s[3][1]), a7 = fmaxf(s[3][2], s[3][3]);
        float b0 = fmaxf(fmaxf(a0, a1), fmaxf(a2, a3));
        float b1 = fmaxf(fmaxf(a4, a5), fmaxf(a6, a7));
        float pmax = fmaxf(b0, b1);
        pmax = fmaxf(pmax, __shfl_xor(pmax, 16));
        pmax = fmaxf(pmax, __shfl_xor(pmax, 32));

        // defer-max (T13): rescale only if some row grew past threshold (exp2 units)
        if (__any(pmax > m_i + 11.54f)) {
            float mnew = fmaxf(m_i, pmax);
            float sc = exp2f(m_i - mnew);
            m_i = mnew;
            l_i *= sc;
#pragma unroll
            for (int j = 0; j < 4; j++) {
                float scj = __shfl(sc, 4 * lg + j);   // sc for q = 4*lg+j lives at lane q
#pragma unroll
                for (int vt = 0; vt < 4; vt++) acc[vt][j] *= scj;
            }
        }

        // P = exp2(s - m), packed to bf16 pairs, rowsum
#pragma unroll
        for (int k16 = 0; k16 < 4; k16++) {
#pragma unroll
            for (int j = 0; j < 4; j++) s[k16][j] = exp2f(s[k16][j] - m_i);
        }
        float r0 = (s[0][0] + s[0][1]) + (s[0][2] + s[0][3]);
        float r1 = (s[1][0] + s[1][1]) + (s[1][2] + s[1][3]);
        float r2 = (s[2][0] + s[2][1]) + (s[2][2] + s[2][3]);
        float r3 = (s[3][0] + s[3][1]) + (s[3][2] + s[3][3]);
        float rowsum = (r0 + r1) + (r2 + r3);
        rowsum += __shfl_xor(rowsum, 16);
        rowsum += __shfl_xor(rowsum, 32);
        l_i += rowsum;

        // exchange P[key][q] -> A-frag P[q][key] via per-wave swizzled LDS
#pragma unroll
        for (int k16 = 0; k16 < 4; k16++) {
            int pk0 = cvt_pk_bf16(s[k16][0], s[k16][1]);
            int pk1 = cvt_pk_bf16(s[k16][2], s[k16][3]);
            int pbase = 8 * k16 + 2 * lg;
            pw[lr * 32 + ((pbase + 0) ^ pswz)] = pk0;
            pw[lr * 32 + ((pbase + 1) ^ pswz)] = pk1;
        }
        bf16x8 pa0 = *(const bf16x8*)&pw[lr * 32 + ((4 * lg) ^ pswz)];        // keys 0..31
        bf16x8 pa1 = *(const bf16x8*)&pw[lr * 32 + ((16 + 4 * lg) ^ pswz)];   // keys 32..63

#pragma unroll
        for (int vt = 0; vt < 4; vt++) {
            int dr = vt * 16 + lr;
            bf16x8 vf0 = *(const bf16x8*)&Vlds[cur][dr * 64 + ((0 + lg) ^ (dr & 7)) * 8];
            bf16x8 vf1 = *(const bf16x8*)&Vlds[cur][dr * 64 + ((4 + lg) ^ (dr & 7)) * 8];
            acc[vt] = __builtin_amdgcn_mfma_f32_16x16x32_bf16(pa0, vf0, acc[vt], 0, 0, 0);
            acc[vt] = __builtin_amdgcn_mfma_f32_16x16x32_bf16(pa1, vf1, acc[vt], 0, 0, 0);
        }

        asm volatile("s_waitcnt vmcnt(0)" ::: "memory");
        __syncthreads();
    }

    // store attn out: [b*1025+q][h*64 + d] bf16; gather l for q = lg*4+j
    float inv[4];
#pragma unroll
    for (int j = 0; j < 4; j++) inv[j] = 1.0f / __shfl(l_i, 4 * lg + j);
#pragma unroll
    for (int vt = 0; vt < 4; vt++) {
#pragma unroll
        for (int j = 0; j < 4; j++) {
            int qrow = qt * 64 + w * 16 + lg * 4 + j;
            if (qrow < SEQ) {
                AO[((size_t)(b * SEQ + qrow)) * DIM + h * HD64 + vt * 16 + lr] =
                    f2bf_rne(acc[vt][j] * inv[j]);
            }
        }
    }
}

// ---------------- output projection GEMM + bias ----------------
__global__ __launch_bounds__(256) void proj_gemm_kernel(
    const short* __restrict__ ab, const short* __restrict__ wb,
    const float* __restrict__ bias, float* __restrict__ out)
{
    __shared__ short Alds[2][128 * 32];
    __shared__ short Blds[2][128 * 32];
    const int tid = threadIdx.x;
    const int lane = tid & 63, w = tid >> 6;
    const int wm = w >> 1, wn = w & 1;
    const int lr = lane & 15, lg = lane >> 4;
    const int tile = xcd_chunk_swizzle(blockIdx.x, 129 * 6);
    const int mt = tile / 6, nt = tile - (tile / 6) * 6;

    f32x4 acc[4][4];
#pragma unroll
    for (int i = 0; i < 4; i++)
#pragma unroll
        for (int j = 0; j < 4; j++) acc[i][j] = (f32x4)0.0f;

    auto stage = [&](int buf, int kt) {
#pragma unroll
        for (int i = 0; i < 2; i++) {
            int c = i * 256 + tid;
            int row = c >> 2, cc = c & 3;
            int gr = mt * 128 + row; if (gr > M_ROWS - 1) gr = M_ROWS - 1;
            gload_lds16(ab + (size_t)gr * DIM + kt * 32 + cc * 8, &Alds[buf][c * 8]);
            int gb = nt * 128 + row;   // < 768 always
            gload_lds16(wb + (size_t)gb * DIM + kt * 32 + cc * 8, &Blds[buf][c * 8]);
        }
    };

    stage(0, 0);
    asm volatile("s_waitcnt vmcnt(0)" ::: "memory");
    __syncthreads();

    for (int kt = 0; kt < 24; ++kt) {
        int cur = kt & 1;
        if (kt < 23) stage(cur ^ 1, kt + 1);

        bf16x8 af[4], bfr[4];
#pragma unroll
        for (int mi = 0; mi < 4; mi++)
            af[mi] = *(const bf16x8*)&Alds[cur][(wm * 64 + mi * 16 + lr) * 32 + lg * 8];
#pragma unroll
        for (int ni = 0; ni < 4; ni++)
            bfr[ni] = *(const bf16x8*)&Blds[cur][(wn * 64 + ni * 16 + lr) * 32 + lg * 8];
#pragma unroll
        for (int mi = 0; mi < 4; mi++)
#pragma unroll
            for (int ni = 0; ni < 4; ni++)
                acc[mi][ni] = __builtin_amdgcn_mfma_f32_16x16x32_bf16(af[mi], bfr[ni], acc[mi][ni], 0, 0, 0);

        asm volatile("s_waitcnt vmcnt(0)" ::: "memory");
        __syncthreads();
    }

#pragma unroll
    for (int ni = 0; ni < 4; ni++) {
        int e = nt * 128 + wn * 64 + ni * 16 + lr;
        float bv = bias[e];
#pragma unroll
        for (int mi = 0; mi < 4; mi++) {
#pragma unroll
            for (int j = 0; j < 4; j++) {
                int m = mt * 128 + wm * 64 + mi * 16 + lg * 4 + j;
                if (m < M_ROWS) out[(size_t)m * DIM + e] = acc[mi][ni][j] + bv;
            }
        }
    }
}

extern "C" void kernel_launch(void* const* d_in, const int* in_sizes, int n_in,
                              void* d_out, int out_size, void* d_ws, size_t ws_size,
                              hipStream_t stream) {
    const float* x     = (const float*)d_in[0];
    const float* fcos  = (const float*)d_in[1];
    const float* fsin  = (const float*)d_in[2];
    const float* wqkv  = (const float*)d_in[3];
    const float* wproj = (const float*)d_in[4];
    const float* bproj = (const float*)d_in[5];
    float* out = (float*)d_out;

    char* ws = (char*)d_ws;
    size_t off = 0;
    auto salloc = [&](size_t bytes) { void* p = ws + off; off += (bytes + 255) & ~(size_t)255; return p; };
    short* xb     = (short*)salloc((size_t)M_ROWS * DIM * 2);
    short* wqkvb  = (short*)salloc((size_t)2304 * DIM * 2);
    short* wprojb = (short*)salloc((size_t)DIM * DIM * 2);
    short* Qb     = (short*)salloc((size_t)192 * SEQ * HD64 * 2);
    short* Kb     = (short*)salloc((size_t)192 * SEQ * HD64 * 2);
    short* VTb    = (short*)salloc((size_t)192 * HD64 * NPAD * 2);
    short* AO     = (short*)salloc((size_t)M_ROWS * DIM * 2);

    {
        int n4 = M_ROWS * DIM / 4;
        f2bf_kernel<<<(n4 + 255) / 256, 256, 0, stream>>>(x, xb, n4);
    }
    {
        int n4 = 2304 * DIM / 4;
        f2bf_kernel<<<(n4 + 255) / 256, 256, 0, stream>>>(wqkv, wqkvb, n4);
    }
    {
        int n4 = DIM * DIM / 4;
        f2bf_kernel<<<(n4 + 255) / 256, 256, 0, stream>>>(wproj, wprojb, n4);
    }

    qkv_gemm_kernel<<<129 * 18, 256, 0, stream>>>(xb, wqkvb, fcos, fsin, Qb, Kb, VTb);
    attn_kernel<<<17 * 192, 256, 0, stream>>>(Qb, Kb, VTb, AO);
    proj_gemm_kernel<<<129 * 6, 256, 0, stream>>>(AO, wprojb, bproj, out);
}

// Round 4
// 336.410 us; speedup vs baseline: 1.3099x; 1.0577x over previous
//
#include <hip/hip_runtime.h>
#include <stdint.h>

#define NH 12
#define HD64 64
#define SEQ 1025
#define M_ROWS (16 * SEQ)   // 16400
#define DIM 768
#define NPAD 1088           // 17 * 64, keeps V^T rows 16B-aligned

typedef __attribute__((ext_vector_type(8))) short bf16x8;
typedef __attribute__((ext_vector_type(4))) float f32x4;
typedef __attribute__((ext_vector_type(4))) short s16x4;

#define VMCNT(n) asm volatile("s_waitcnt vmcnt(" #n ")" ::: "memory")
#define LGKMCNT0 asm volatile("s_waitcnt lgkmcnt(0)" ::: "memory")

__device__ __forceinline__ short f2bf_rne(float f) {
    union { float f; uint32_t u; } c; c.f = f;
    uint32_t u = c.u + 0x7fffu + ((c.u >> 16) & 1u);
    return (short)(u >> 16);
}

__device__ __forceinline__ int cvt_pk_bf16(float lo, float hi) {
    int r;
    asm("v_cvt_pk_bf16_f32 %0, %1, %2" : "=v"(r) : "v"(lo), "v"(hi));
    return r;
}

__device__ __forceinline__ void gload_lds16(const void* g, void* l) {
    __builtin_amdgcn_global_load_lds(
        (const __attribute__((address_space(1))) void*)g,
        (__attribute__((address_space(3))) void*)l, 16, 0, 0);
}

// T1: XCD-chunked bijective swizzle (m204).
__device__ __forceinline__ int xcd_chunk_swizzle(int orig, int nwg) {
    int q = nwg >> 3, r = nwg & 7;
    int xcd = orig & 7, i = orig >> 3;
    int start = (xcd < r) ? xcd * (q + 1) : r * (q + 1) + (xcd - r) * q;
    return start + i;
}

// ---------------- fp32 -> bf16 conversion ----------------
__global__ void f2bf_kernel(const float* __restrict__ in, short* __restrict__ out, int n4) {
    int i = blockIdx.x * blockDim.x + threadIdx.x;
    if (i < n4) {
        f32x4 f = ((const f32x4*)in)[i];
        s16x4 o;
        o[0] = f2bf_rne(f[0]); o[1] = f2bf_rne(f[1]);
        o[2] = f2bf_rne(f[2]); o[3] = f2bf_rne(f[3]);
        ((s16x4*)out)[i] = o;
    }
}

// ---------------- QKV GEMM + RoPE epilogue ----------------
// Depth-3 counted-vmcnt pipeline (T4): 3 LDS buffers, vmcnt(8) in steady state
// (2 tiles always in flight), raw s_barrier (no compiler vmcnt(0) drain).
__global__ __launch_bounds__(256) void qkv_gemm_kernel(
    const short* __restrict__ xb, const short* __restrict__ wb,
    const float* __restrict__ fcos, const float* __restrict__ fsin,
    short* __restrict__ Qb, short* __restrict__ Kb, short* __restrict__ VTb)
{
    __shared__ short Alds[3][128 * 32];
    __shared__ short Blds[3][128 * 32];
    const int tid = threadIdx.x;
    const int lane = tid & 63, w = tid >> 6;
    const int wm = w >> 1, wn = w & 1;
    const int lr = lane & 15, lg = lane >> 4;
    const int tile = xcd_chunk_swizzle(blockIdx.x, 129 * 18);
    const int mt = tile / 18, nt = tile - (tile / 18) * 18;

    // per-thread staging pointers (loop-invariant; only +kt*32 per step)
    const int c0 = tid, c1 = 256 + tid;
    int ra0 = mt * 128 + (c0 >> 2); if (ra0 > M_ROWS - 1) ra0 = M_ROWS - 1;
    int ra1 = mt * 128 + (c1 >> 2); if (ra1 > M_ROWS - 1) ra1 = M_ROWS - 1;
    const short* gA0 = xb + (size_t)ra0 * DIM + (c0 & 3) * 8;
    const short* gA1 = xb + (size_t)ra1 * DIM + (c1 & 3) * 8;
    const short* gB0 = wb + (size_t)(nt * 128 + (c0 >> 2)) * DIM + (c0 & 3) * 8;
    const short* gB1 = wb + (size_t)(nt * 128 + (c1 >> 2)) * DIM + (c1 & 3) * 8;
    short* lA0 = &Alds[0][0] + c0 * 8;
    short* lA1 = &Alds[0][0] + c1 * 8;
    short* lB0 = &Blds[0][0] + c0 * 8;
    short* lB1 = &Blds[0][0] + c1 * 8;

    auto stage = [&](int buf, int kt) {
        const int ko = kt * 32;
        const int lo = buf * (128 * 32);
        gload_lds16(gA0 + ko, lA0 + lo);
        gload_lds16(gA1 + ko, lA1 + lo);
        gload_lds16(gB0 + ko, lB0 + lo);
        gload_lds16(gB1 + ko, lB1 + lo);
    };

    f32x4 acc[4][4];
#pragma unroll
    for (int i = 0; i < 4; i++)
#pragma unroll
        for (int j = 0; j < 4; j++) acc[i][j] = (f32x4)0.0f;

    stage(0, 0); stage(1, 1); stage(2, 2);

    int cur = 0;
    for (int t = 0; t < 24; ++t) {
        if (t <= 21) { VMCNT(8); } else if (t == 22) { VMCNT(4); } else { VMCNT(0); }
        __builtin_amdgcn_s_barrier();   // tile t confirmed by every wave

        bf16x8 af[4], bfr[4];
        const short* Ab = &Alds[0][0] + cur * (128 * 32);
        const short* Bb = &Blds[0][0] + cur * (128 * 32);
#pragma unroll
        for (int mi = 0; mi < 4; mi++)
            af[mi] = *(const bf16x8*)&Ab[(wm * 64 + mi * 16 + lr) * 32 + lg * 8];
#pragma unroll
        for (int ni = 0; ni < 4; ni++)
            bfr[ni] = *(const bf16x8*)&Bb[(wn * 64 + ni * 16 + lr) * 32 + lg * 8];

        if (t <= 20) {
            LGKMCNT0;                        // my reads of buf[cur] complete
            __builtin_amdgcn_s_barrier();    // everyone's reads complete
            stage(cur, t + 3);               // overwrite freed buffer; MFMA hides it
        }

#pragma unroll
        for (int mi = 0; mi < 4; mi++)
#pragma unroll
            for (int ni = 0; ni < 4; ni++)
                acc[mi][ni] = __builtin_amdgcn_mfma_f32_16x16x32_bf16(af[mi], bfr[ni], acc[mi][ni], 0, 0, 0);

        cur = (cur == 2) ? 0 : cur + 1;
    }

    // epilogue: RoPE (pairs are adjacent cols = lane^1), scale Q, scatter
#pragma unroll
    for (int mi = 0; mi < 4; mi++) {
        int mbase = mt * 128 + wm * 64 + mi * 16 + lg * 4;
#pragma unroll
        for (int j = 0; j < 4; j++) {
            int m = mbase + j;
            bool valid = (m < M_ROWS);
            int mm = valid ? m : 0;
            int b = mm / SEQ;
            int n = mm - b * SEQ;
#pragma unroll
            for (int ni = 0; ni < 4; ni++) {
                int e = nt * 128 + wn * 64 + ni * 16 + lr;
                int qkv = e / DIM;
                int rem = e - qkv * DIM;
                int h = rem >> 6, d = rem & 63;
                float v = acc[mi][ni][j];
                float vo = __shfl_xor(v, 1);       // partner col e^1 (uniform exec)
                float outv = v;
                if (qkv < 2 && n > 0) {
                    float cs = fcos[(n - 1) * 32 + (d >> 1)];
                    float sn = fsin[(n - 1) * 32 + (d >> 1)];
                    outv = (d & 1) ? (vo * sn + v * cs) : (v * cs - vo * sn);
                }
                if (qkv == 0) outv *= 0.180336881f;   // 1/sqrt(64) * log2(e)
                if (valid) {
                    short bv = f2bf_rne(outv);
                    size_t bh = (size_t)b * NH + h;
                    if (qkv == 0)      Qb[(bh * SEQ + n) * HD64 + d] = bv;
                    else if (qkv == 1) Kb[(bh * SEQ + n) * HD64 + d] = bv;
                    else               VTb[(bh * HD64 + d) * NPAD + n] = bv;
                }
            }
        }
    }
}

// ---------------- flash attention ----------------
// (unchanged from round 3: swapped QK^T, in-register softmax, dbuf K/V)
__global__ __launch_bounds__(256) void attn_kernel(
    const short* __restrict__ Qb, const short* __restrict__ Kb,
    const short* __restrict__ VTb, short* __restrict__ AO)
{
    __shared__ short Klds[2][64 * 64];
    __shared__ short Vlds[2][64 * 64];
    __shared__ int Plds[4][16 * 32];   // per-wave P exchange: [q=lr][32 key-pair dwords]
    const int tid = threadIdx.x;
    const int lane = tid & 63, w = tid >> 6;
    const int lr = lane & 15, lg = lane >> 4;
    const int tile = xcd_chunk_swizzle(blockIdx.x, 17 * 192);
    const int bh = tile / 17, qt = tile - (tile / 17) * 17;
    const int b = bh / NH, h = bh - b * NH;

    const short* Qp = Qb + (size_t)bh * SEQ * HD64;
    const short* Kp = Kb + (size_t)bh * SEQ * HD64;
    const short* Vp = VTb + (size_t)bh * HD64 * NPAD;

    int qr = qt * 64 + w * 16 + lr; if (qr > SEQ - 1) qr = SEQ - 1;
    bf16x8 qf0 = *(const bf16x8*)&Qp[(size_t)qr * HD64 + 0 + lg * 8];
    bf16x8 qf1 = *(const bf16x8*)&Qp[(size_t)qr * HD64 + 32 + lg * 8];

    float m_i = -1e30f, l_i = 0.f;      // per-lane scalars, q = lr
    f32x4 acc[4];
#pragma unroll
    for (int vt = 0; vt < 4; vt++) acc[vt] = (f32x4)0.0f;

    int* pw = &Plds[w][0];
    const int pswz = (lr & 3) << 3;     // xor-swizzle on key-pair index (bits 3,4)

    auto stageKV = [&](int buf, int t) {
        int k0 = t * 64;
#pragma unroll
        for (int i = 0; i < 2; i++) {
            int c = i * 256 + tid;
            int row = c >> 3, ccd = c & 7;
            int cl = ccd ^ (row & 7);
            int krow = k0 + row; if (krow > SEQ - 1) krow = SEQ - 1;
            gload_lds16(Kp + (size_t)krow * HD64 + cl * 8, &Klds[buf][c * 8]);
            gload_lds16(Vp + (size_t)row * NPAD + k0 + cl * 8, &Vlds[buf][c * 8]);
        }
    };

    stageKV(0, 0);
    asm volatile("s_waitcnt vmcnt(0)" ::: "memory");
    __syncthreads();

    for (int t = 0; t < 17; ++t) {
        int cur = t & 1;
        if (t < 16) stageKV(cur ^ 1, t + 1);   // prefetch next K/V under compute

        // swapped QK^T: s[k16] rows = key = k16*16 + lg*4 + j, col q = lr
        f32x4 s[4];
#pragma unroll
        for (int k16 = 0; k16 < 4; k16++) {
            int krow = k16 * 16 + lr;   // A-frag row this lane LOADS
            bf16x8 kf0 = *(const bf16x8*)&Klds[cur][krow * 64 + ((0 + lg) ^ (krow & 7)) * 8];
            bf16x8 kf1 = *(const bf16x8*)&Klds[cur][krow * 64 + ((4 + lg) ^ (krow & 7)) * 8];
            f32x4 d = (f32x4)0.0f;
            d = __builtin_amdgcn_mfma_f32_16x16x32_bf16(kf0, qf0, d, 0, 0, 0);
            d = __builtin_amdgcn_mfma_f32_16x16x32_bf16(kf1, qf1, d, 0, 0, 0);
            s[k16] = d;
        }
        if (t == 16) {
            // only key 1024 (k16==0, lg==0, j==0) is valid
            s[0][0] = (lg == 0) ? s[0][0] : -1e30f;
            s[0][1] = -1e30f; s[0][2] = -1e30f; s[0][3] = -1e30f;
#pragma unroll
            for (int k16 = 1; k16 < 4; k16++) { s[k16][0] = -1e30f; s[k16][1] = -1e30f; s[k16][2] = -1e30f; s[k16][3] = -1e30f; }
        }

        // local max tree over 16 values
        float a0 = fmaxf(s[0][0], s[0][1]), a1 = fmaxf(s[0][2], s[0][3]);
        float a2 = fmaxf(s[1][0], s[1][1]), a3 = fmaxf(s[1][2], s[1][3]);
        float a4 = fmaxf(s[2][0], s[2][1]), a5 = fmaxf(s[2][2], s[2][3]);
        float a6 = fmaxf(s[3][0], s[3][1]), a7 = fmaxf(s[3][2], s[3][3]);
        float b0 = fmaxf(fmaxf(a0, a1), fmaxf(a2, a3));
        float b1 = fmaxf(fmaxf(a4, a5), fmaxf(a6, a7));
        float pmax = fmaxf(b0, b1);
        pmax = fmaxf(pmax, __shfl_xor(pmax, 16));
        pmax = fmaxf(pmax, __shfl_xor(pmax, 32));

        // defer-max (T13): rescale only if some row grew past threshold (exp2 units)
        if (__any(pmax > m_i + 11.54f)) {
            float mnew = fmaxf(m_i, pmax);
            float sc = exp2f(m_i - mnew);
            m_i = mnew;
            l_i *= sc;
#pragma unroll
            for (int j = 0; j < 4; j++) {
                float scj = __shfl(sc, 4 * lg + j);   // sc for q = 4*lg+j lives at lane q
#pragma unroll
                for (int vt = 0; vt < 4; vt++) acc[vt][j] *= scj;
            }
        }

        // P = exp2(s - m), packed to bf16 pairs, rowsum
#pragma unroll
        for (int k16 = 0; k16 < 4; k16++) {
#pragma unroll
            for (int j = 0; j < 4; j++) s[k16][j] = exp2f(s[k16][j] - m_i);
        }
        float r0 = (s[0][0] + s[0][1]) + (s[0][2] + s[0][3]);
        float r1 = (s[1][0] + s[1][1]) + (s[1][2] + s[1][3]);
        float r2 = (s[2][0] + s[2][1]) + (s[2][2] + s[2][3]);
        float r3 = (s[3][0] + s[3][1]) + (s[3][2] + s[3][3]);
        float rowsum = (r0 + r1) + (r2 + r3);
        rowsum += __shfl_xor(rowsum, 16);
        rowsum += __shfl_xor(rowsum, 32);
        l_i += rowsum;

        // exchange P[key][q] -> A-frag P[q][key] via per-wave swizzled LDS
#pragma unroll
        for (int k16 = 0; k16 < 4; k16++) {
            int pk0 = cvt_pk_bf16(s[k16][0], s[k16][1]);
            int pk1 = cvt_pk_bf16(s[k16][2], s[k16][3]);
            int pbase = 8 * k16 + 2 * lg;
            pw[lr * 32 + ((pbase + 0) ^ pswz)] = pk0;
            pw[lr * 32 + ((pbase + 1) ^ pswz)] = pk1;
        }
        bf16x8 pa0 = *(const bf16x8*)&pw[lr * 32 + ((4 * lg) ^ pswz)];        // keys 0..31
        bf16x8 pa1 = *(const bf16x8*)&pw[lr * 32 + ((16 + 4 * lg) ^ pswz)];   // keys 32..63

#pragma unroll
        for (int vt = 0; vt < 4; vt++) {
            int dr = vt * 16 + lr;
            bf16x8 vf0 = *(const bf16x8*)&Vlds[cur][dr * 64 + ((0 + lg) ^ (dr & 7)) * 8];
            bf16x8 vf1 = *(const bf16x8*)&Vlds[cur][dr * 64 + ((4 + lg) ^ (dr & 7)) * 8];
            acc[vt] = __builtin_amdgcn_mfma_f32_16x16x32_bf16(pa0, vf0, acc[vt], 0, 0, 0);
            acc[vt] = __builtin_amdgcn_mfma_f32_16x16x32_bf16(pa1, vf1, acc[vt], 0, 0, 0);
        }

        asm volatile("s_waitcnt vmcnt(0)" ::: "memory");
        __syncthreads();
    }

    // store attn out: [b*1025+q][h*64 + d] bf16; gather l for q = lg*4+j
    float inv[4];
#pragma unroll
    for (int j = 0; j < 4; j++) inv[j] = 1.0f / __shfl(l_i, 4 * lg + j);
#pragma unroll
    for (int vt = 0; vt < 4; vt++) {
#pragma unroll
        for (int j = 0; j < 4; j++) {
            int qrow = qt * 64 + w * 16 + lg * 4 + j;
            if (qrow < SEQ) {
                AO[((size_t)(b * SEQ + qrow)) * DIM + h * HD64 + vt * 16 + lr] =
                    f2bf_rne(acc[vt][j] * inv[j]);
            }
        }
    }
}

// ---------------- output projection GEMM + bias ----------------
// Same depth-3 counted-vmcnt pipeline as qkv_gemm.
__global__ __launch_bounds__(256) void proj_gemm_kernel(
    const short* __restrict__ ab, const short* __restrict__ wb,
    const float* __restrict__ bias, float* __restrict__ out)
{
    __shared__ short Alds[3][128 * 32];
    __shared__ short Blds[3][128 * 32];
    const int tid = threadIdx.x;
    const int lane = tid & 63, w = tid >> 6;
    const int wm = w >> 1, wn = w & 1;
    const int lr = lane & 15, lg = lane >> 4;
    const int tile = xcd_chunk_swizzle(blockIdx.x, 129 * 6);
    const int mt = tile / 6, nt = tile - (tile / 6) * 6;

    const int c0 = tid, c1 = 256 + tid;
    int ra0 = mt * 128 + (c0 >> 2); if (ra0 > M_ROWS - 1) ra0 = M_ROWS - 1;
    int ra1 = mt * 128 + (c1 >> 2); if (ra1 > M_ROWS - 1) ra1 = M_ROWS - 1;
    const short* gA0 = ab + (size_t)ra0 * DIM + (c0 & 3) * 8;
    const short* gA1 = ab + (size_t)ra1 * DIM + (c1 & 3) * 8;
    const short* gB0 = wb + (size_t)(nt * 128 + (c0 >> 2)) * DIM + (c0 & 3) * 8;
    const short* gB1 = wb + (size_t)(nt * 128 + (c1 >> 2)) * DIM + (c1 & 3) * 8;
    short* lA0 = &Alds[0][0] + c0 * 8;
    short* lA1 = &Alds[0][0] + c1 * 8;
    short* lB0 = &Blds[0][0] + c0 * 8;
    short* lB1 = &Blds[0][0] + c1 * 8;

    auto stage = [&](int buf, int kt) {
        const int ko = kt * 32;
        const int lo = buf * (128 * 32);
        gload_lds16(gA0 + ko, lA0 + lo);
        gload_lds16(gA1 + ko, lA1 + lo);
        gload_lds16(gB0 + ko, lB0 + lo);
        gload_lds16(gB1 + ko, lB1 + lo);
    };

    f32x4 acc[4][4];
#pragma unroll
    for (int i = 0; i < 4; i++)
#pragma unroll
        for (int j = 0; j < 4; j++) acc[i][j] = (f32x4)0.0f;

    stage(0, 0); stage(1, 1); stage(2, 2);

    int cur = 0;
    for (int t = 0; t < 24; ++t) {
        if (t <= 21) { VMCNT(8); } else if (t == 22) { VMCNT(4); } else { VMCNT(0); }
        __builtin_amdgcn_s_barrier();

        bf16x8 af[4], bfr[4];
        const short* Ab = &Alds[0][0] + cur * (128 * 32);
        const short* Bb = &Blds[0][0] + cur * (128 * 32);
#pragma unroll
        for (int mi = 0; mi < 4; mi++)
            af[mi] = *(const bf16x8*)&Ab[(wm * 64 + mi * 16 + lr) * 32 + lg * 8];
#pragma unroll
        for (int ni = 0; ni < 4; ni++)
            bfr[ni] = *(const bf16x8*)&Bb[(wn * 64 + ni * 16 + lr) * 32 + lg * 8];

        if (t <= 20) {
            LGKMCNT0;
            __builtin_amdgcn_s_barrier();
            stage(cur, t + 3);
        }

#pragma unroll
        for (int mi = 0; mi < 4; mi++)
#pragma unroll
            for (int ni = 0; ni < 4; ni++)
                acc[mi][ni] = __builtin_amdgcn_mfma_f32_16x16x32_bf16(af[mi], bfr[ni], acc[mi][ni], 0, 0, 0);

        cur = (cur == 2) ? 0 : cur + 1;
    }

#pragma unroll
    for (int ni = 0; ni < 4; ni++) {
        int e = nt * 128 + wn * 64 + ni * 16 + lr;
        float bv = bias[e];
#pragma unroll
        for (int mi = 0; mi < 4; mi++) {
#pragma unroll
            for (int j = 0; j < 4; j++) {
                int m = mt * 128 + wm * 64 + mi * 16 + lg * 4 + j;
                if (m < M_ROWS) out[(size_t)m * DIM + e] = acc[mi][ni][j] + bv;
            }
        }
    }
}

extern "C" void kernel_launch(void* const* d_in, const int* in_sizes, int n_in,
                              void* d_out, int out_size, void* d_ws, size_t ws_size,
                              hipStream_t stream) {
    const float* x     = (const float*)d_in[0];
    const float* fcos  = (const float*)d_in[1];
    const float* fsin  = (const float*)d_in[2];
    const float* wqkv  = (const float*)d_in[3];
    const float* wproj = (const float*)d_in[4];
    const float* bproj = (const float*)d_in[5];
    float* out = (float*)d_out;

    char* ws = (char*)d_ws;
    size_t off = 0;
    auto salloc = [&](size_t bytes) { void* p = ws + off; off += (bytes + 255) & ~(size_t)255; return p; };
    short* xb     = (short*)salloc((size_t)M_ROWS * DIM * 2);
    short* wqkvb  = (short*)salloc((size_t)2304 * DIM * 2);
    short* wprojb = (short*)salloc((size_t)DIM * DIM * 2);
    short* Qb     = (short*)salloc((size_t)192 * SEQ * HD64 * 2);
    short* Kb     = (short*)salloc((size_t)192 * SEQ * HD64 * 2);
    short* VTb    = (short*)salloc((size_t)192 * HD64 * NPAD * 2);
    short* AO     = (short*)salloc((size_t)M_ROWS * DIM * 2);

    {
        int n4 = M_ROWS * DIM / 4;
        f2bf_kernel<<<(n4 + 255) / 256, 256, 0, stream>>>(x, xb, n4);
    }
    {
        int n4 = 2304 * DIM / 4;
        f2bf_kernel<<<(n4 + 255) / 256, 256, 0, stream>>>(wqkv, wqkvb, n4);
    }
    {
        int n4 = DIM * DIM / 4;
        f2bf_kernel<<<(n4 + 255) / 256, 256, 0, stream>>>(wproj, wprojb, n4);
    }

    qkv_gemm_kernel<<<129 * 18, 256, 0, stream>>>(xb, wqkvb, fcos, fsin, Qb, Kb, VTb);
    attn_kernel<<<17 * 192, 256, 0, stream>>>(Qb, Kb, VTb, AO);
    proj_gemm_kernel<<<129 * 6, 256, 0, stream>>>(AO, wprojb, bproj, out);
}